// Round 1
// baseline (298.869 us; speedup 1.0000x reference)
//
#include <hip/hip_runtime.h>

// Problem constants
constexpr int TB = 16;        // batch
constexpr int NP = 2048;      // pre neurons
constexpr int NQ = 2048;      // post neurons
constexpr int TT = 256;       // timesteps
constexpr int KH = TB * TT;   // 4096, half-K
constexpr int KT = 2 * KH;    // 8192, total contraction length

typedef unsigned short ushort_t;
typedef __attribute__((ext_vector_type(8))) __bf16 bf16x8;
typedef __attribute__((ext_vector_type(4))) float f32x4;

__device__ __forceinline__ ushort_t f2bf(float f) {
    unsigned u = __builtin_bit_cast(unsigned, f);
    // round-to-nearest-even (inputs are finite, no NaN handling needed)
    u = (u + 0x7FFFu + ((u >> 16) & 1u)) >> 16;
    return (ushort_t)u;
}

union Pack8 { ushort_t u[8]; uint4 v; };

// ---------------------------------------------------------------------------
// Stage 1: compute traces, quantize to bf16, build A[P][KT] and B[Q][KT].
//   A[p][b*T+t]      = x_pre(t,b,p)
//   A[p][KH+b*T+t]   = pre(t,b,p)
//   B[q][b*T+t]      = post(t,b,q) * (A_plus + 0.0065*x_trip(t,b,q))
//   B[q][KH+b*T+t]   = -A_minus * x_post(t,b,q)
// Also accumulates the total spike count (exact integers in fp32).
// ---------------------------------------------------------------------------
__global__ __launch_bounds__(256) void stage_traces(
    const float* __restrict__ pre, const float* __restrict__ post,
    const float* __restrict__ mApP, const float* __restrict__ mAmP,
    ushort_t* __restrict__ Ab, ushort_t* __restrict__ Bb,
    float* __restrict__ ssum)
{
    const int n = blockIdx.x * 256 + threadIdx.x;   // 0..65535
    const bool isPre = (n < TB * NP);
    const int m = isPre ? n : n - TB * NP;          // row id: b*2048 + neuron
    const int b = m >> 11;
    const int r = m & 2047;

    const float4* src4 = (const float4*)((isPre ? pre : post) + (size_t)m * TT);
    ushort_t* o0 = (isPre ? Ab : Bb) + (size_t)r * KT + b * TT;
    ushort_t* o1 = o0 + KH;

    const float d_fast = 0.95122942450071400910f; // exp(-0.001/0.02)
    const float d_x    = 0.99014786386058731819f; // exp(-0.001/0.101)

    float cnt = 0.f;

    if (isPre) {
        float x = 0.f;
        for (int t8 = 0; t8 < TT / 8; ++t8) {
            float4 u0 = src4[t8 * 2];
            float4 u1 = src4[t8 * 2 + 1];
            float sv[8] = {u0.x, u0.y, u0.z, u0.w, u1.x, u1.y, u1.z, u1.w};
            Pack8 pt, ps;
            #pragma unroll
            for (int j = 0; j < 8; ++j) {
                float s = sv[j];
                pt.u[j] = f2bf(x);                       // trace used at step t
                ps.u[j] = (s != 0.f) ? 0x3F80u : 0u;     // bf16(spike) exact
                cnt += s;
                x = d_fast * (x + s);                    // spike added after
            }
            *(uint4*)(o0 + t8 * 8) = pt.v;
            *(uint4*)(o1 + t8 * 8) = ps.v;
        }
    } else {
        const float Ap = *mApP;
        const float Am = *mAmP;
        float xm = 0.f, xt = 0.f;
        for (int t8 = 0; t8 < TT / 8; ++t8) {
            float4 u0 = src4[t8 * 2];
            float4 u1 = src4[t8 * 2 + 1];
            float sv[8] = {u0.x, u0.y, u0.z, u0.w, u1.x, u1.y, u1.z, u1.w};
            Pack8 p1, p2;
            #pragma unroll
            for (int j = 0; j < 8; ++j) {
                float s = sv[j];
                p1.u[j] = (s != 0.f) ? f2bf(Ap + 0.0065f * xt) : 0u;
                p2.u[j] = f2bf(-Am * xm);
                cnt += s;
                xm = d_fast * (xm + s);
                xt = d_x * (xt + s);
            }
            *(uint4*)(o0 + t8 * 8) = p1.v;
            *(uint4*)(o1 + t8 * 8) = p2.v;
        }
    }

    // wave-level reduction, one atomic per wave (all values exact integers)
    #pragma unroll
    for (int off = 32; off > 0; off >>= 1)
        cnt += __shfl_down(cnt, off);
    if ((threadIdx.x & 63) == 0)
        atomicAdd(ssum, cnt);
}

// ---------------------------------------------------------------------------
// Stage 2: C[p][q] = clip(W[p][q] + scale * sum_k A[p][k]*B[q][k], -2, 2)
// 128x128 tile per block, 4 waves, each wave a 64x64 quadrant as 4x4 grid of
// 16x16x32 bf16 MFMA tiles. global_load_lds (16B) staging with XOR swizzle on
// the 16B-chunk index to avoid LDS bank conflicts on the frag reads.
// ---------------------------------------------------------------------------
__device__ __forceinline__ void async16(const ushort_t* g, ushort_t* l) {
    __builtin_amdgcn_global_load_lds(
        (const __attribute__((address_space(1))) unsigned int*)g,
        (__attribute__((address_space(3))) unsigned int*)l,
        16, 0, 0);
}

__global__ __launch_bounds__(256) void gemm_update(
    const ushort_t* __restrict__ Ab, const ushort_t* __restrict__ Bb,
    const float* __restrict__ W, const float* __restrict__ ssum,
    float* __restrict__ Out)
{
    __shared__ ushort_t As[128 * 64];
    __shared__ ushort_t Bs[128 * 64];

    const int tid  = threadIdx.x;
    const int lane = tid & 63;
    const int wv   = tid >> 6;       // 0..3
    const int wr   = wv >> 1;        // wave row quadrant
    const int wc   = wv & 1;         // wave col quadrant
    const int quad = lane >> 4;      // 0..3
    const int m16  = lane & 15;

    const int p0 = blockIdx.y * 128;
    const int q0 = blockIdx.x * 128;

    f32x4 acc[4][4] = {};

    for (int kt = 0; kt < KT / 64; ++kt) {
        const int k0 = kt * 64;
        __syncthreads();   // previous iter's frag reads done before overwrite
        #pragma unroll
        for (int r = 0; r < 4; ++r) {
            const int c   = r * 256 + tid;       // 16B chunk id, 0..1023
            const int row = c >> 3;              // 0..127
            const int kk8 = (c & 7) ^ (row & 7); // swizzled source chunk
            const ushort_t* ga = Ab + (size_t)(p0 + row) * KT + k0 + kk8 * 8;
            const ushort_t* gb = Bb + (size_t)(q0 + row) * KT + k0 + kk8 * 8;
            // wave-uniform LDS base; HW adds lane*16
            ushort_t* la = &As[(r * 256 + wv * 64) * 8];
            ushort_t* lb = &Bs[(r * 256 + wv * 64) * 8];
            async16(ga, la);
            async16(gb, lb);
        }
        __syncthreads();   // drains vmcnt(0): staged data visible

        #pragma unroll
        for (int ks = 0; ks < 2; ++ks) {
            bf16x8 af[4], bf[4];
            #pragma unroll
            for (int i = 0; i < 4; ++i) {
                const int row  = wr * 64 + i * 16 + m16;
                const int slot = (ks * 4 + quad) ^ (row & 7);
                af[i] = *(const bf16x8*)&As[row * 64 + slot * 8];
            }
            #pragma unroll
            for (int j = 0; j < 4; ++j) {
                const int row  = wc * 64 + j * 16 + m16;
                const int slot = (ks * 4 + quad) ^ (row & 7);
                bf[j] = *(const bf16x8*)&Bs[row * 64 + slot * 8];
            }
            #pragma unroll
            for (int i = 0; i < 4; ++i)
                #pragma unroll
                for (int j = 0; j < 4; ++j)
                    acc[i][j] = __builtin_amdgcn_mfma_f32_16x16x32_bf16(
                        af[i], bf[j], acc[i][j], 0, 0, 0);
        }
    }

    // epilogue: scale from exact spike count, add weights, clip
    const float s = *ssum;
    const float scale = sqrtf(0.1f / (s * (1.0f / 4096.0f) + 1e-6f));

    #pragma unroll
    for (int i = 0; i < 4; ++i) {
        const int prow = p0 + wr * 64 + i * 16 + quad * 4;
        #pragma unroll
        for (int j = 0; j < 4; ++j) {
            const int qcol = q0 + wc * 64 + j * 16 + m16;
            #pragma unroll
            for (int r2 = 0; r2 < 4; ++r2) {
                const size_t idx = (size_t)(prow + r2) * NQ + qcol;
                float v = W[idx] + scale * acc[i][j][r2];
                v = fminf(fmaxf(v, -2.0f), 2.0f);
                Out[idx] = v;
            }
        }
    }
}

extern "C" void kernel_launch(void* const* d_in, const int* in_sizes, int n_in,
                              void* d_out, int out_size, void* d_ws, size_t ws_size,
                              hipStream_t stream) {
    const float* pre  = (const float*)d_in[0];
    const float* post = (const float*)d_in[1];
    const float* W    = (const float*)d_in[2];
    const float* mAp  = (const float*)d_in[3];
    const float* mAm  = (const float*)d_in[4];
    float* out = (float*)d_out;

    char* ws = (char*)d_ws;
    float* ssum   = (float*)ws;
    ushort_t* Ab  = (ushort_t*)(ws + 256);
    ushort_t* Bb  = (ushort_t*)(ws + 256 + (size_t)NP * KT * sizeof(ushort_t));

    hipMemsetAsync(ssum, 0, sizeof(float), stream);

    stage_traces<<<dim3((TB * NP + TB * NQ) / 256), dim3(256), 0, stream>>>(
        pre, post, mAp, mAm, Ab, Bb, ssum);

    gemm_update<<<dim3(NQ / 128, NP / 128), dim3(256), 0, stream>>>(
        Ab, Bb, W, ssum, out);
}

// Round 2
// 296.511 us; speedup vs baseline: 1.0080x; 1.0080x over previous
//
#include <hip/hip_runtime.h>

// Problem constants
constexpr int TB = 16;        // batch
constexpr int NP = 2048;      // pre neurons
constexpr int NQ = 2048;      // post neurons
constexpr int TT = 256;       // timesteps
constexpr int KH = TB * TT;   // 4096, half-K
constexpr int KT = 2 * KH;    // 8192, total contraction length

typedef unsigned short ushort_t;
typedef __attribute__((ext_vector_type(8))) __bf16 bf16x8;
typedef __attribute__((ext_vector_type(4))) float f32x4;

__device__ __forceinline__ ushort_t f2bf(float f) {
    unsigned u = __builtin_bit_cast(unsigned, f);
    u = (u + 0x7FFFu + ((u >> 16) & 1u)) >> 16;   // RNE, inputs finite
    return (ushort_t)u;
}

union Pack4 { ushort_t u[4]; uint2 v; };

// Decay powers (constexpr chains; ~1e-6 rel err, far below bf16 rounding)
constexpr float DF1 = 0.95122942450071400910f;            // exp(-0.05)
constexpr float DF2 = DF1 * DF1;
constexpr float DF3 = DF2 * DF1;
constexpr float DF4 = DF2 * DF2;
constexpr float DF8 = DF4 * DF4;
constexpr float DF16 = DF8 * DF8;
constexpr float DF32 = DF16 * DF16;
constexpr float DF64 = DF32 * DF32;
constexpr float DF128 = DF64 * DF64;

constexpr float DX1 = 0.99014786386058731819f;            // exp(-1/101)
constexpr float DX2 = DX1 * DX1;
constexpr float DX3 = DX2 * DX1;
constexpr float DX4 = DX2 * DX2;
constexpr float DX8 = DX4 * DX4;
constexpr float DX16 = DX8 * DX8;
constexpr float DX32 = DX16 * DX16;
constexpr float DX64 = DX32 * DX32;
constexpr float DX128 = DX64 * DX64;

// Kogge-Stone inclusive scan of affine maps x->d4*x+C across 64 lanes,
// returning the EXCLUSIVE carry-in for each lane (trace at chunk start).
// pw[k] = d4^(2^k), compile-time.
template <int K>
__device__ __forceinline__ float scan_step(float b, float pw, int lane) {
    float t = __shfl_up(b, K, 64);
    return (lane >= K) ? fmaf(pw, t, b) : b;
}

__device__ __forceinline__ float wave_carry(float C, int lane,
                                            float p1, float p2, float p4,
                                            float p8, float p16, float p32) {
    float b = C;
    b = scan_step<1>(b, p1, lane);
    b = scan_step<2>(b, p2, lane);
    b = scan_step<4>(b, p4, lane);
    b = scan_step<8>(b, p8, lane);
    b = scan_step<16>(b, p16, lane);
    b = scan_step<32>(b, p32, lane);
    float xin = __shfl_up(b, 1, 64);
    return (lane == 0) ? 0.f : xin;
}

// ---------------------------------------------------------------------------
// Stage 1: one WAVE per (b, neuron) row. Lane l owns timesteps 4l..4l+3.
// Exponential-trace scan parallelized via affine-map wave scan.
//   A[p][b*T+t]      = x_pre(t,b,p)            A[p][KH+b*T+t] = pre(t,b,p)
//   B[q][b*T+t]      = post*(A_plus+0.0065*x_trip)
//   B[q][KH+b*T+t]   = -A_minus*x_post
// Spike counts accumulate into 256 partial slots (exact integers in fp32).
// ---------------------------------------------------------------------------
__global__ __launch_bounds__(256) void stage_traces(
    const float* __restrict__ pre, const float* __restrict__ post,
    const float* __restrict__ mApP, const float* __restrict__ mAmP,
    ushort_t* __restrict__ Ab, ushort_t* __restrict__ Bb,
    float* __restrict__ partials)
{
    const int tid = threadIdx.x;
    const int lane = tid & 63;
    const int wv = tid >> 6;
    const int rowg = blockIdx.x * 4 + wv;          // 0..65535
    const bool isPre = rowg < TB * NP;
    const int m = isPre ? rowg : rowg - TB * NP;   // b*2048 + neuron
    const int b = m >> 11;
    const int r = m & 2047;

    const float4 s4 = ((const float4*)((isPre ? pre : post) + (size_t)m * TT))[lane];
    const float s0 = s4.x, s1 = s4.y, s2 = s4.z, s3 = s4.w;
    float cnt = (s0 + s1) + (s2 + s3);

    ushort_t* o0 = (isPre ? Ab : Bb) + (size_t)r * KT + b * TT + lane * 4;
    ushort_t* o1 = o0 + KH;

    // fast-decay trace (pre: x_pre; post: x_post) — needed by both paths
    const float Cf = fmaf(DF4, s0, fmaf(DF3, s1, fmaf(DF2, s2, DF1 * s3)));
    const float xinf = wave_carry(Cf, lane, DF4, DF8, DF16, DF32, DF64, DF128);
    const float xf0 = xinf;
    const float xf1 = fmaf(DF1, xinf, DF1 * s0);
    const float xf2 = fmaf(DF2, xinf, fmaf(DF2, s0, DF1 * s1));
    const float xf3 = fmaf(DF3, xinf, fmaf(DF3, s0, fmaf(DF2, s1, DF1 * s2)));

    Pack4 pa, pb;
    if (isPre) {
        pa.u[0] = f2bf(xf0); pa.u[1] = f2bf(xf1);
        pa.u[2] = f2bf(xf2); pa.u[3] = f2bf(xf3);
        pb.u[0] = (s0 != 0.f) ? 0x3F80u : 0u;
        pb.u[1] = (s1 != 0.f) ? 0x3F80u : 0u;
        pb.u[2] = (s2 != 0.f) ? 0x3F80u : 0u;
        pb.u[3] = (s3 != 0.f) ? 0x3F80u : 0u;
    } else {
        // triplet (slow) trace
        const float Cx = fmaf(DX4, s0, fmaf(DX3, s1, fmaf(DX2, s2, DX1 * s3)));
        const float xinx = wave_carry(Cx, lane, DX4, DX8, DX16, DX32, DX64, DX128);
        const float xt0 = xinx;
        const float xt1 = fmaf(DX1, xinx, DX1 * s0);
        const float xt2 = fmaf(DX2, xinx, fmaf(DX2, s0, DX1 * s1));
        const float xt3 = fmaf(DX3, xinx, fmaf(DX3, s0, fmaf(DX2, s1, DX1 * s2)));

        const float Ap = *mApP;
        const float Am = *mAmP;
        pa.u[0] = (s0 != 0.f) ? f2bf(fmaf(0.0065f, xt0, Ap)) : 0u;
        pa.u[1] = (s1 != 0.f) ? f2bf(fmaf(0.0065f, xt1, Ap)) : 0u;
        pa.u[2] = (s2 != 0.f) ? f2bf(fmaf(0.0065f, xt2, Ap)) : 0u;
        pa.u[3] = (s3 != 0.f) ? f2bf(fmaf(0.0065f, xt3, Ap)) : 0u;
        pb.u[0] = f2bf(-Am * xf0); pb.u[1] = f2bf(-Am * xf1);
        pb.u[2] = f2bf(-Am * xf2); pb.u[3] = f2bf(-Am * xf3);
    }
    *(uint2*)o0 = pa.v;
    *(uint2*)o1 = pb.v;

    // wave reduce spike count; one atomic per wave, 256 slots
    #pragma unroll
    for (int off = 32; off > 0; off >>= 1)
        cnt += __shfl_down(cnt, off, 64);
    if (lane == 0)
        atomicAdd(&partials[blockIdx.x & 255], cnt);
}

// ---------------------------------------------------------------------------
// Stage 2: split-K GEMM. P_z[p][q] = sum_{k in z-half} A[p][k]*B[q][k]
// 128x128 tile, 4 waves x (64x64), 16x16x32 bf16 MFMA, global_load_lds 16B
// staging with XOR swizzle. grid (16,16,2) = 512 blocks -> 2 blocks/CU.
// ---------------------------------------------------------------------------
__device__ __forceinline__ void async16(const ushort_t* g, ushort_t* l) {
    __builtin_amdgcn_global_load_lds(
        (const __attribute__((address_space(1))) unsigned int*)g,
        (__attribute__((address_space(3))) unsigned int*)l,
        16, 0, 0);
}

__global__ __launch_bounds__(256) void gemm_split(
    const ushort_t* __restrict__ Ab, const ushort_t* __restrict__ Bb,
    float* __restrict__ P0, float* __restrict__ P1)
{
    __shared__ ushort_t As[128 * 64];
    __shared__ ushort_t Bs[128 * 64];

    const int tid  = threadIdx.x;
    const int lane = tid & 63;
    const int wv   = tid >> 6;
    const int wr   = wv >> 1;
    const int wc   = wv & 1;
    const int quad = lane >> 4;
    const int m16  = lane & 15;

    const int p0 = blockIdx.y * 128;
    const int q0 = blockIdx.x * 128;
    const int kbase = blockIdx.z * (KT / 2);

    f32x4 acc[4][4] = {};

    for (int kt = 0; kt < KT / 128; ++kt) {
        const int k0 = kbase + kt * 64;
        __syncthreads();
        #pragma unroll
        for (int r = 0; r < 4; ++r) {
            const int c   = r * 256 + tid;
            const int row = c >> 3;
            const int kk8 = (c & 7) ^ (row & 7);
            const ushort_t* ga = Ab + (size_t)(p0 + row) * KT + k0 + kk8 * 8;
            const ushort_t* gb = Bb + (size_t)(q0 + row) * KT + k0 + kk8 * 8;
            ushort_t* la = &As[(r * 256 + wv * 64) * 8];
            ushort_t* lb = &Bs[(r * 256 + wv * 64) * 8];
            async16(ga, la);
            async16(gb, lb);
        }
        __syncthreads();

        #pragma unroll
        for (int ks = 0; ks < 2; ++ks) {
            bf16x8 af[4], bf[4];
            #pragma unroll
            for (int i = 0; i < 4; ++i) {
                const int row  = wr * 64 + i * 16 + m16;
                const int slot = (ks * 4 + quad) ^ (row & 7);
                af[i] = *(const bf16x8*)&As[row * 64 + slot * 8];
            }
            #pragma unroll
            for (int j = 0; j < 4; ++j) {
                const int row  = wc * 64 + j * 16 + m16;
                const int slot = (ks * 4 + quad) ^ (row & 7);
                bf[j] = *(const bf16x8*)&Bs[row * 64 + slot * 8];
            }
            #pragma unroll
            for (int i = 0; i < 4; ++i)
                #pragma unroll
                for (int j = 0; j < 4; ++j)
                    acc[i][j] = __builtin_amdgcn_mfma_f32_16x16x32_bf16(
                        af[i], bf[j], acc[i][j], 0, 0, 0);
        }
    }

    float* P = blockIdx.z ? P1 : P0;
    #pragma unroll
    for (int i = 0; i < 4; ++i) {
        const int prow = p0 + wr * 64 + i * 16 + quad * 4;
        #pragma unroll
        for (int j = 0; j < 4; ++j) {
            const int qcol = q0 + wc * 64 + j * 16 + m16;
            #pragma unroll
            for (int r2 = 0; r2 < 4; ++r2)
                P[(size_t)(prow + r2) * NQ + qcol] = acc[i][j][r2];
        }
    }
}

// ---------------------------------------------------------------------------
// Stage 3: Out = clip(W + scale*(P0+P1), -2, 2); P0 lives in d_out (in-place).
// scale derived from the 256 spike-count partials (exact integers).
// ---------------------------------------------------------------------------
__global__ __launch_bounds__(256) void merge_out(
    const float* __restrict__ W, const float* __restrict__ P1,
    const float* __restrict__ partials, float* __restrict__ Out)
{
    __shared__ float s_scale;
    const int tid = threadIdx.x;
    if (tid < 64) {
        float v = (partials[tid] + partials[tid + 64]) +
                  (partials[tid + 128] + partials[tid + 192]);
        #pragma unroll
        for (int off = 32; off > 0; off >>= 1)
            v += __shfl_down(v, off, 64);
        if (tid == 0)
            s_scale = sqrtf(0.1f / (v * (1.0f / 4096.0f) + 1e-6f));
    }
    __syncthreads();
    const float scale = s_scale;

    const size_t i4 = (size_t)blockIdx.x * 256 + tid;
    float4 w = ((const float4*)W)[i4];
    float4 a = ((const float4*)Out)[i4];
    float4 c = ((const float4*)P1)[i4];
    float4 o;
    o.x = fminf(fmaxf(fmaf(scale, a.x + c.x, w.x), -2.f), 2.f);
    o.y = fminf(fmaxf(fmaf(scale, a.y + c.y, w.y), -2.f), 2.f);
    o.z = fminf(fmaxf(fmaf(scale, a.z + c.z, w.z), -2.f), 2.f);
    o.w = fminf(fmaxf(fmaf(scale, a.w + c.w, w.w), -2.f), 2.f);
    ((float4*)Out)[i4] = o;
}

extern "C" void kernel_launch(void* const* d_in, const int* in_sizes, int n_in,
                              void* d_out, int out_size, void* d_ws, size_t ws_size,
                              hipStream_t stream) {
    const float* pre  = (const float*)d_in[0];
    const float* post = (const float*)d_in[1];
    const float* W    = (const float*)d_in[2];
    const float* mAp  = (const float*)d_in[3];
    const float* mAm  = (const float*)d_in[4];
    float* out = (float*)d_out;

    char* ws = (char*)d_ws;
    float* partials = (float*)ws;                                   // 1 KB
    ushort_t* Ab = (ushort_t*)(ws + 1024);                          // 32 MB
    ushort_t* Bb = (ushort_t*)(ws + 1024 + (size_t)NP * KT * 2);    // 32 MB
    float* P1    = (float*)(ws + 1024 + 2 * (size_t)NP * KT * 2);   // 16.8 MB

    hipMemsetAsync(partials, 0, 256 * sizeof(float), stream);

    stage_traces<<<dim3((TB * NP + TB * NQ) / 4), dim3(256), 0, stream>>>(
        pre, post, mAp, mAm, Ab, Bb, partials);

    gemm_split<<<dim3(NQ / 128, NP / 128, 2), dim3(256), 0, stream>>>(
        Ab, Bb, out, P1);

    merge_out<<<dim3(NP * NQ / 1024), dim3(256), 0, stream>>>(
        W, P1, partials, out);
}

// Round 3
// 216.629 us; speedup vs baseline: 1.3796x; 1.3687x over previous
//
#include <hip/hip_runtime.h>

// Problem constants
constexpr int TB = 16;        // batch
constexpr int NP = 2048;      // pre neurons
constexpr int NQ = 2048;      // post neurons
constexpr int TT = 256;       // timesteps
constexpr int KH = TB * TT;   // 4096, half-K
constexpr int KT = 2 * KH;    // 8192, total contraction length

typedef unsigned short ushort_t;
typedef __attribute__((ext_vector_type(8))) __bf16 bf16x8;
typedef __attribute__((ext_vector_type(4))) float f32x4;

__device__ __forceinline__ ushort_t f2bf(float f) {
    unsigned u = __builtin_bit_cast(unsigned, f);
    u = (u + 0x7FFFu + ((u >> 16) & 1u)) >> 16;   // RNE, inputs finite
    return (ushort_t)u;
}

union Pack16 { ushort_t u[16]; uint4 v[2]; };

// Decay powers (constexpr chains; ~1e-6 rel err, far below bf16 rounding)
constexpr float DF1 = 0.95122942450071400910f;            // exp(-0.05)
constexpr float DF2 = DF1 * DF1;
constexpr float DF4 = DF2 * DF2;
constexpr float DF8 = DF4 * DF4;
constexpr float DF16 = DF8 * DF8;
constexpr float DF32 = DF16 * DF16;
constexpr float DF64 = DF32 * DF32;
constexpr float DF128 = DF64 * DF64;

constexpr float DX1 = 0.99014786386058731819f;            // exp(-1/101)
constexpr float DX2 = DX1 * DX1;
constexpr float DX4 = DX2 * DX2;
constexpr float DX8 = DX4 * DX4;
constexpr float DX16 = DX8 * DX8;
constexpr float DX32 = DX16 * DX16;
constexpr float DX64 = DX32 * DX32;
constexpr float DX128 = DX64 * DX64;

// One segmented (16-lane) Kogge-Stone step over affine-map offsets.
// Window of length W ending at lane sl combines with the previous window:
// b' = b + d16^W * b_prev, guarded to stay inside the 16-lane segment.
template <int K>
__device__ __forceinline__ float seg_step(float b, float pw, int sl) {
    float t = __shfl_up(b, K, 64);
    return (sl >= K) ? fmaf(pw, t, b) : b;
}

// ---------------------------------------------------------------------------
// Stage 1: 16 lanes per (b, neuron) row; lane owns timesteps sl*16..sl*16+15.
// Local affine fold (16 serial fma) -> 4-step segmented scan -> serial expand.
//   A[p][b*T+t]    = x_pre(t,b,p)            A[p][KH+b*T+t] = pre(t,b,p)
//   B[q][b*T+t]    = post*(A_plus+0.0065*x_trip)
//   B[q][KH+b*T+t] = -A_minus*x_post
// Spike count: wave reduce -> block reduce -> ONE atomic per block into
// 64 slots spread 64B apart (no same-line atomic pileup).
// ---------------------------------------------------------------------------
__global__ __launch_bounds__(256) void stage_traces(
    const float* __restrict__ pre, const float* __restrict__ post,
    const float* __restrict__ mApP, const float* __restrict__ mAmP,
    ushort_t* __restrict__ Ab, ushort_t* __restrict__ Bb,
    float* __restrict__ partials)
{
    const int tid  = threadIdx.x;
    const int lane = tid & 63;
    const int wv   = tid >> 6;
    const int sl   = lane & 15;       // segment lane (time chunk)
    const int seg  = lane >> 4;       // row within wave
    const int rowg = blockIdx.x * 16 + wv * 4 + seg;   // 0..65535
    const bool isPre = rowg < TB * NP;                 // block-uniform
    const int m = isPre ? rowg : rowg - TB * NP;       // b*2048 + neuron
    const int b = m >> 11;
    const int r = m & 2047;

    const float4* src = (const float4*)((isPre ? pre : post) + (size_t)m * TT);
    float f[16];
    #pragma unroll
    for (int j = 0; j < 4; ++j) {
        float4 u = src[sl * 4 + j];
        f[4 * j] = u.x; f[4 * j + 1] = u.y; f[4 * j + 2] = u.z; f[4 * j + 3] = u.w;
    }
    float cnt = 0.f;
    #pragma unroll
    for (int j = 0; j < 16; ++j) cnt += f[j];

    // ---- fast-decay trace (x_pre for pre rows, x_post for post rows) ----
    float Cf = 0.f;
    #pragma unroll
    for (int j = 0; j < 16; ++j) Cf = DF1 * (Cf + f[j]);   // local chunk offset
    float bs = Cf;
    bs = seg_step<1>(bs, DF16, sl);
    bs = seg_step<2>(bs, DF32, sl);
    bs = seg_step<4>(bs, DF64, sl);
    bs = seg_step<8>(bs, DF128, sl);
    float xinf = __shfl_up(bs, 1, 64);
    if (sl == 0) xinf = 0.f;

    float xf[16];
    {
        float x = xinf;
        #pragma unroll
        for (int j = 0; j < 16; ++j) { xf[j] = x; x = DF1 * (x + f[j]); }
    }

    Pack16 pa, pb;
    if (isPre) {
        #pragma unroll
        for (int j = 0; j < 16; ++j) {
            pa.u[j] = f2bf(xf[j]);
            pb.u[j] = (f[j] != 0.f) ? 0x3F80u : 0u;   // bf16(spike) exact
        }
    } else {
        // ---- slow (triplet) trace ----
        float Cx = 0.f;
        #pragma unroll
        for (int j = 0; j < 16; ++j) Cx = DX1 * (Cx + f[j]);
        float bx = Cx;
        bx = seg_step<1>(bx, DX16, sl);
        bx = seg_step<2>(bx, DX32, sl);
        bx = seg_step<4>(bx, DX64, sl);
        bx = seg_step<8>(bx, DX128, sl);
        float xint = __shfl_up(bx, 1, 64);
        if (sl == 0) xint = 0.f;

        const float Ap = *mApP;
        const float Am = *mAmP;
        float xt = xint;
        #pragma unroll
        for (int j = 0; j < 16; ++j) {
            pa.u[j] = (f[j] != 0.f) ? f2bf(fmaf(0.0065f, xt, Ap)) : 0u;
            pb.u[j] = f2bf(-Am * xf[j]);
            xt = DX1 * (xt + f[j]);
        }
    }

    ushort_t* o0 = (isPre ? Ab : Bb) + (size_t)r * KT + b * TT + sl * 16;
    *(uint4*)o0       = pa.v[0];
    *(uint4*)(o0 + 8) = pa.v[1];
    *(uint4*)(o0 + KH)     = pb.v[0];
    *(uint4*)(o0 + KH + 8) = pb.v[1];

    // spike count: wave reduce -> block reduce -> one spread atomic per block
    #pragma unroll
    for (int off = 32; off > 0; off >>= 1)
        cnt += __shfl_down(cnt, off, 64);
    __shared__ float wsum[4];
    if (lane == 0) wsum[wv] = cnt;
    __syncthreads();
    if (tid == 0) {
        float s = (wsum[0] + wsum[1]) + (wsum[2] + wsum[3]);
        atomicAdd(&partials[(blockIdx.x & 63) * 16], s);  // 64 slots, 64B apart
    }
}

// ---------------------------------------------------------------------------
// Stage 2: split-K GEMM with DOUBLE-BUFFERED LDS prefetch.
// Per iter: barrier -> issue async stage of tile k+1 -> compute tile k.
// One barrier per iter; the vmcnt(0) drain at the barrier waits on loads that
// had a full compute phase to land. 128x128 tile, 4 waves x (64x64),
// 16x16x32 bf16 MFMA, XOR-swizzled LDS. grid (16,16,2) -> 2 blocks/CU (128KB).
// ---------------------------------------------------------------------------
__device__ __forceinline__ void async16(const ushort_t* g, ushort_t* l) {
    __builtin_amdgcn_global_load_lds(
        (const __attribute__((address_space(1))) unsigned int*)g,
        (__attribute__((address_space(3))) unsigned int*)l,
        16, 0, 0);
}

__global__ __launch_bounds__(256) void gemm_split(
    const ushort_t* __restrict__ Ab, const ushort_t* __restrict__ Bb,
    float* __restrict__ P0, float* __restrict__ P1)
{
    __shared__ ushort_t As[2][128 * 64];
    __shared__ ushort_t Bs[2][128 * 64];

    const int tid  = threadIdx.x;
    const int lane = tid & 63;
    const int wv   = tid >> 6;
    const int wr   = wv >> 1;
    const int wc   = wv & 1;
    const int quad = lane >> 4;
    const int m16  = lane & 15;

    const int p0 = blockIdx.y * 128;
    const int q0 = blockIdx.x * 128;
    const int kbase = blockIdx.z * (KT / 2);

    // per-thread staging constants (chunk id c = r*256+tid, row = c>>3, swizzle)
    const int ldsbase = wv * 64 * 8;   // + r*256*8 per r; wave-uniform

    f32x4 acc[4][4] = {};

    auto stage = [&](int buf, int k0) {
        #pragma unroll
        for (int rr = 0; rr < 4; ++rr) {
            const int c   = rr * 256 + tid;
            const int row = c >> 3;
            const int kk8 = (c & 7) ^ (row & 7);
            const ushort_t* ga = Ab + (size_t)(p0 + row) * KT + k0 + kk8 * 8;
            const ushort_t* gb = Bb + (size_t)(q0 + row) * KT + k0 + kk8 * 8;
            async16(ga, &As[buf][rr * 256 * 8 + ldsbase]);
            async16(gb, &Bs[buf][rr * 256 * 8 + ldsbase]);
        }
    };

    constexpr int NIT = (KT / 2) / 64;   // 64 iterations
    stage(0, kbase);

    for (int kt = 0; kt < NIT; ++kt) {
        const int cur = kt & 1;
        __syncthreads();                         // stage(kt) landed; prev reads done
        if (kt + 1 < NIT)
            stage(cur ^ 1, kbase + (kt + 1) * 64);   // prefetch, no wait

        #pragma unroll
        for (int ks = 0; ks < 2; ++ks) {
            bf16x8 af[4], bf[4];
            #pragma unroll
            for (int i = 0; i < 4; ++i) {
                const int row  = wr * 64 + i * 16 + m16;
                const int slot = (ks * 4 + quad) ^ (row & 7);
                af[i] = *(const bf16x8*)&As[cur][row * 64 + slot * 8];
            }
            #pragma unroll
            for (int j = 0; j < 4; ++j) {
                const int row  = wc * 64 + j * 16 + m16;
                const int slot = (ks * 4 + quad) ^ (row & 7);
                bf[j] = *(const bf16x8*)&Bs[cur][row * 64 + slot * 8];
            }
            #pragma unroll
            for (int i = 0; i < 4; ++i)
                #pragma unroll
                for (int j = 0; j < 4; ++j)
                    acc[i][j] = __builtin_amdgcn_mfma_f32_16x16x32_bf16(
                        af[i], bf[j], acc[i][j], 0, 0, 0);
        }
    }

    float* P = blockIdx.z ? P1 : P0;
    #pragma unroll
    for (int i = 0; i < 4; ++i) {
        const int prow = p0 + wr * 64 + i * 16 + quad * 4;
        #pragma unroll
        for (int j = 0; j < 4; ++j) {
            const int qcol = q0 + wc * 64 + j * 16 + m16;
            #pragma unroll
            for (int r2 = 0; r2 < 4; ++r2)
                P[(size_t)(prow + r2) * NQ + qcol] = acc[i][j][r2];
        }
    }
}

// ---------------------------------------------------------------------------
// Stage 3: Out = clip(W + scale*(P0+P1), -2, 2); P0 lives in d_out (in-place).
// scale from the 64 spread spike-count slots (exact integers).
// ---------------------------------------------------------------------------
__global__ __launch_bounds__(256) void merge_out(
    const float* __restrict__ W, const float* __restrict__ P1,
    const float* __restrict__ partials, float* __restrict__ Out)
{
    __shared__ float s_scale;
    const int tid = threadIdx.x;
    if (tid < 64) {
        float v = partials[tid * 16];
        #pragma unroll
        for (int off = 32; off > 0; off >>= 1)
            v += __shfl_down(v, off, 64);
        if (tid == 0)
            s_scale = sqrtf(0.1f / (v * (1.0f / 4096.0f) + 1e-6f));
    }
    __syncthreads();
    const float scale = s_scale;

    const size_t i4 = (size_t)blockIdx.x * 256 + tid;
    float4 w = ((const float4*)W)[i4];
    float4 a = ((const float4*)Out)[i4];
    float4 c = ((const float4*)P1)[i4];
    float4 o;
    o.x = fminf(fmaxf(fmaf(scale, a.x + c.x, w.x), -2.f), 2.f);
    o.y = fminf(fmaxf(fmaf(scale, a.y + c.y, w.y), -2.f), 2.f);
    o.z = fminf(fmaxf(fmaf(scale, a.z + c.z, w.z), -2.f), 2.f);
    o.w = fminf(fmaxf(fmaf(scale, a.w + c.w, w.w), -2.f), 2.f);
    ((float4*)Out)[i4] = o;
}

extern "C" void kernel_launch(void* const* d_in, const int* in_sizes, int n_in,
                              void* d_out, int out_size, void* d_ws, size_t ws_size,
                              hipStream_t stream) {
    const float* pre  = (const float*)d_in[0];
    const float* post = (const float*)d_in[1];
    const float* W    = (const float*)d_in[2];
    const float* mAp  = (const float*)d_in[3];
    const float* mAm  = (const float*)d_in[4];
    float* out = (float*)d_out;

    char* ws = (char*)d_ws;
    float* partials = (float*)ws;                                    // 16 KB
    ushort_t* Ab = (ushort_t*)(ws + 16384);                          // 32 MB
    ushort_t* Bb = (ushort_t*)(ws + 16384 + (size_t)NP * KT * 2);    // 32 MB
    float* P1    = (float*)(ws + 16384 + 2 * (size_t)NP * KT * 2);   // 16.8 MB

    hipMemsetAsync(partials, 0, 64 * 16 * sizeof(float), stream);

    stage_traces<<<dim3((TB * NP + TB * NQ) / 16), dim3(256), 0, stream>>>(
        pre, post, mAp, mAm, Ab, Bb, partials);

    gemm_split<<<dim3(NQ / 128, NP / 128, 2), dim3(256), 0, stream>>>(
        Ab, Bb, out, P1);

    merge_out<<<dim3(NP * NQ / 1024), dim3(256), 0, stream>>>(
        W, P1, partials, out);
}